// Round 2
// 1539.779 us; speedup vs baseline: 1.0623x; 1.0623x over previous
//
#include <hip/hip_runtime.h>
#include <cstdint>
#include <cstddef>

#define NB 4
#define NS 4096
#define ND 2048
#define NH 16
#define NHD 128
#define NT 1024
#define NF 8192

typedef __bf16 bf16;
typedef __bf16 bf16x8 __attribute__((ext_vector_type(8)));
typedef __bf16 bf16x4 __attribute__((ext_vector_type(4)));
typedef float  f32x4  __attribute__((ext_vector_type(4)));

typedef const __attribute__((address_space(1))) void* gptr_t;
typedef __attribute__((address_space(3))) void* lptr_t;

__device__ __forceinline__ float wave_sum(float v) {
#pragma unroll
    for (int off = 32; off > 0; off >>= 1) v += __shfl_xor(v, off);
    return v;
}
__device__ __forceinline__ float wave_max(float v) {
#pragma unroll
    for (int off = 32; off > 0; off >>= 1) v = fmaxf(v, __shfl_xor(v, off));
    return v;
}

// ---------------------------------------------------------------------------
// Router: logits[row] = dot(x[row,:], w_router)   (row = b*NS+s)
// ---------------------------------------------------------------------------
__global__ __launch_bounds__(256) void router_k(const float* __restrict__ x,
                                                const float* __restrict__ wr,
                                                float* __restrict__ logits) {
    __shared__ float r4[4];
    long long row = blockIdx.x;
    const float4* xr = (const float4*)(x + row * ND);
    const float4* w4 = (const float4*)wr;
    float p = 0.f;
    for (int i = threadIdx.x; i < ND / 4; i += 256) {
        float4 a = xr[i], b = w4[i];
        p += a.x * b.x + a.y * b.y + a.z * b.z + a.w * b.w;
    }
    p = wave_sum(p);
    if ((threadIdx.x & 63) == 0) r4[threadIdx.x >> 6] = p;
    __syncthreads();
    if (threadIdx.x == 0) logits[row] = r4[0] + r4[1] + r4[2] + r4[3];
}

// ---------------------------------------------------------------------------
// Top-K (exact, matches jax.lax.top_k tie-break) + index sort + router softmax.
// ---------------------------------------------------------------------------
__global__ __launch_bounds__(1024) void topk_k(const float* __restrict__ logits,
                                               int* __restrict__ sel,
                                               float* __restrict__ rw) {
    __shared__ unsigned long long keys[NS];   // 32 KB
    __shared__ float r16[16];
    __shared__ float bmax, bsum;
    const int bb = blockIdx.x;
    const int tid = threadIdx.x;
    const float* lg = logits + (long long)bb * NS;

    for (int i = tid; i < NS; i += 1024) {
        unsigned u = __float_as_uint(lg[i]);
        u = (u & 0x80000000u) ? ~u : (u | 0x80000000u);   // order-preserving map
        keys[i] = ((unsigned long long)u << 32) | (unsigned)(NS - 1 - i);
    }
    __syncthreads();
    for (int k = 2; k <= NS; k <<= 1) {
        for (int j = k >> 1; j > 0; j >>= 1) {
            for (int i = tid; i < NS; i += 1024) {
                int ixj = i ^ j;
                if (ixj > i) {
                    unsigned long long a = keys[i], c = keys[ixj];
                    bool up = ((i & k) == 0);
                    if (up ? (a < c) : (a > c)) { keys[i] = c; keys[ixj] = a; }
                }
            }
            __syncthreads();
        }
    }
    unsigned long long a0 = keys[tid];
    __syncthreads();
    {
        unsigned idx_ = NS - 1 - (unsigned)(a0 & 0xFFFFFFFFu);
        unsigned uval = (unsigned)(a0 >> 32);
        keys[tid] = ((unsigned long long)idx_ << 32) | uval;
    }
    __syncthreads();
    for (int k = 2; k <= NT; k <<= 1) {
        for (int j = k >> 1; j > 0; j >>= 1) {
            int i = tid, ixj = i ^ j;
            if (i < NT && ixj > i) {
                unsigned long long a = keys[i], c = keys[ixj];
                bool up = ((i & k) == 0);
                if (up ? (a > c) : (a < c)) { keys[i] = c; keys[ixj] = a; }
            }
            __syncthreads();
        }
    }
    unsigned long long kk = keys[tid];
    int si = (int)(kk >> 32);
    unsigned u = (unsigned)(kk & 0xFFFFFFFFu);
    u = (u & 0x80000000u) ? (u ^ 0x80000000u) : ~u;
    float val = __uint_as_float(u);

    const int wid = tid >> 6, lane = tid & 63;
    float mx = wave_max(val);
    if (lane == 0) r16[wid] = mx;
    __syncthreads();
    if (tid == 0) {
        float m = r16[0];
        for (int i = 1; i < 16; i++) m = fmaxf(m, r16[i]);
        bmax = m;
    }
    __syncthreads();
    float e = __expf(val - bmax);
    float s = wave_sum(e);
    if (lane == 0) r16[wid] = s;
    __syncthreads();
    if (tid == 0) {
        float t = 0.f;
        for (int i = 0; i < 16; i++) t += r16[i];
        bsum = t;
    }
    __syncthreads();
    sel[bb * NT + tid] = si;
    rw[bb * NT + tid] = e / bsum;
}

// ---------------------------------------------------------------------------
// Gather: xf[b,j,:] = x[b, sel[b,j], :]   (float4)
// ---------------------------------------------------------------------------
__global__ __launch_bounds__(256) void gather_k(const float* __restrict__ x,
                                                const int* __restrict__ sel,
                                                float* __restrict__ xf) {
    int gid = blockIdx.x * 256 + threadIdx.x;
    int col = gid & (ND / 4 - 1);
    int row = gid >> 9;
    int bb = row >> 10;
    int s = sel[row];
    ((float4*)xf)[gid] = ((const float4*)x)[((long long)bb * NS + s) * (ND / 4) + col];
}

// ---------------------------------------------------------------------------
// RMSNorm row kernel: out = bf16(x * rsqrt(mean(x^2)+eps) * g)
// ---------------------------------------------------------------------------
__global__ __launch_bounds__(256) void rmsnorm_k(const float* __restrict__ x,
                                                 const float* __restrict__ g,
                                                 bf16* __restrict__ out) {
    __shared__ float r4[4];
    __shared__ float scl;
    long long row = blockIdx.x;
    const float4* xr = (const float4*)(x + row * ND);
    int i0 = threadIdx.x, i1 = threadIdx.x + 256;
    float4 a = xr[i0], b = xr[i1];
    float ss = a.x * a.x + a.y * a.y + a.z * a.z + a.w * a.w +
               b.x * b.x + b.y * b.y + b.z * b.z + b.w * b.w;
    ss = wave_sum(ss);
    if ((threadIdx.x & 63) == 0) r4[threadIdx.x >> 6] = ss;
    __syncthreads();
    if (threadIdx.x == 0)
        scl = rsqrtf((r4[0] + r4[1] + r4[2] + r4[3]) * (1.0f / ND) + 1e-6f);
    __syncthreads();
    float s = scl;
    const float4* g4 = (const float4*)g;
    float4 ga = g4[i0], gb = g4[i1];
    bf16x4 o0, o1;
    o0[0] = (bf16)(a.x * s * ga.x); o0[1] = (bf16)(a.y * s * ga.y);
    o0[2] = (bf16)(a.z * s * ga.z); o0[3] = (bf16)(a.w * s * ga.w);
    o1[0] = (bf16)(b.x * s * gb.x); o1[1] = (bf16)(b.y * s * gb.y);
    o1[2] = (bf16)(b.z * s * gb.z); o1[3] = (bf16)(b.w * s * gb.w);
    *(bf16x4*)(out + row * ND + i0 * 4) = o0;
    *(bf16x4*)(out + row * ND + i1 * 4) = o1;
}

// ---------------------------------------------------------------------------
// Transpose + fp32->bf16: out[c][r] = in[r][c]; in is R x C. dims %32 == 0.
// ---------------------------------------------------------------------------
__global__ __launch_bounds__(256) void transpose_to_bf16(const float* __restrict__ in,
                                                         bf16* __restrict__ out,
                                                         int R, int C) {
    __shared__ float tile[32][33];
    int bx = blockIdx.x * 32;   // col
    int by = blockIdx.y * 32;   // row
    int tx = threadIdx.x & 31;
    int ty = threadIdx.x >> 5;   // 0..7
#pragma unroll
    for (int i = 0; i < 4; i++)
        tile[ty + 8 * i][tx] = in[(long long)(by + ty + 8 * i) * C + bx + tx];
    __syncthreads();
#pragma unroll
    for (int i = 0; i < 4; i++)
        out[(long long)(bx + ty + 8 * i) * R + by + tx] = (bf16)tile[tx][ty + 8 * i];
}

// ---------------------------------------------------------------------------
// RoPE + layout shuffle (reads fused QKV buffer, row stride 3*ND)
// ---------------------------------------------------------------------------
__global__ __launch_bounds__(256) void rope_k(const bf16* __restrict__ QKV,
                                              const float* __restrict__ fr,
                                              bf16* __restrict__ Q,
                                              bf16* __restrict__ K,
                                              bf16* __restrict__ Vt) {
    int gid = blockIdx.x * 256 + threadIdx.x;
    int hd = gid & 63;
    int h = (gid >> 6) & 15;
    int t = (gid >> 10) & (NT - 1);
    int bb = gid >> 20;
    float c = fr[t * 128 + hd * 2 + 0];
    float s = fr[t * 128 + hd * 2 + 1];
    long long base = ((long long)bb * NT + t) * (3 * ND) + h * NHD;
    float q1 = (float)QKV[base + hd],      q2 = (float)QKV[base + hd + 64];
    float k1 = (float)QKV[base + ND + hd], k2 = (float)QKV[base + ND + hd + 64];
    long long ob = (((long long)(bb * NH + h)) * NT + t) * NHD;
    Q[ob + hd]      = (bf16)(q1 * c - q2 * s);
    Q[ob + hd + 64] = (bf16)(q1 * s + q2 * c);
    K[ob + hd]      = (bf16)(k1 * c - k2 * s);
    K[ob + hd + 64] = (bf16)(k1 * s + k2 * c);
    long long vb = ((long long)(bb * NH + h)) * NHD * NT + t;
    Vt[vb + (long long)hd * NT]        = QKV[base + 2 * ND + hd];
    Vt[vb + (long long)(hd + 64) * NT] = QKV[base + 2 * ND + hd + 64];
}

// ---------------------------------------------------------------------------
// Row softmax (T=1024 cols): P = bf16(softmax(scores_row))
// ---------------------------------------------------------------------------
__global__ __launch_bounds__(256) void softmax_k(const float* __restrict__ Sc,
                                                 bf16* __restrict__ P) {
    __shared__ float r4[4];
    __shared__ float bc;
    long long row = blockIdx.x;
    float4 v = ((const float4*)(Sc + row * NT))[threadIdx.x];
    float mx = fmaxf(fmaxf(v.x, v.y), fmaxf(v.z, v.w));
    mx = wave_max(mx);
    if ((threadIdx.x & 63) == 0) r4[threadIdx.x >> 6] = mx;
    __syncthreads();
    if (threadIdx.x == 0) bc = fmaxf(fmaxf(r4[0], r4[1]), fmaxf(r4[2], r4[3]));
    __syncthreads();
    float m = bc;
    float e0 = __expf(v.x - m), e1 = __expf(v.y - m);
    float e2 = __expf(v.z - m), e3 = __expf(v.w - m);
    float ss = wave_sum(e0 + e1 + e2 + e3);
    if ((threadIdx.x & 63) == 0) r4[threadIdx.x >> 6] = ss;
    __syncthreads();
    if (threadIdx.x == 0) bc = 1.f / (r4[0] + r4[1] + r4[2] + r4[3]);
    __syncthreads();
    float inv = bc;
    bf16x4 o;
    o[0] = (bf16)(e0 * inv); o[1] = (bf16)(e1 * inv);
    o[2] = (bf16)(e2 * inv); o[3] = (bf16)(e3 * inv);
    *(bf16x4*)(P + row * NT + threadIdx.x * 4) = o;
}

// ---------------------------------------------------------------------------
__global__ __launch_bounds__(256) void copy_k(const float4* __restrict__ in,
                                              float4* __restrict__ out, long long n) {
    for (long long i = (long long)blockIdx.x * 256 + threadIdx.x; i < n;
         i += (long long)gridDim.x * 256)
        out[i] = in[i];
}

// ---------------------------------------------------------------------------
// MFMA GEMM (m97 structure) — kept for attention shapes (K=128 / N=128).
// MODE 0: C bf16 = alpha*acc     MODE 1: C fp32 = alpha*acc
// ---------------------------------------------------------------------------
template <int MODE>
__global__ __launch_bounds__(256, 2) void gemm_bt(
    const bf16* __restrict__ A, int lda, long long sAz,
    const bf16* __restrict__ Bt, int ldb, long long sBz,
    void* __restrict__ Cv, long long sCz, int ldc,
    int K, float alpha,
    const float* __restrict__ res, const int* __restrict__ selp,
    const float* __restrict__ rwp, float* __restrict__ outp) {
    __shared__ bf16 As[128][32];   // 8 KB, unpadded (global_load_lds layout)
    __shared__ bf16 Bs[128][32];

    const int tid = threadIdx.x;
    const int lane = tid & 63;
    const int wave = tid >> 6;
    const int wm = wave >> 1, wn = wave & 1;
    const int lm = lane & 15, lq = lane >> 4;

    const int m0 = blockIdx.y * 128;
    const int n0 = blockIdx.x * 128;
    const int z = blockIdx.z;

    A += (long long)z * sAz;
    Bt += (long long)z * sBz;

    f32x4 acc[4][4];
#pragma unroll
    for (int i = 0; i < 4; i++)
#pragma unroll
        for (int j = 0; j < 4; j++) {
            f32x4 zz = {0.f, 0.f, 0.f, 0.f};
            acc[i][j] = zz;
        }

    const int sr = wave * 16 + (lane >> 2);
    const int sk = (lane & 3) * 8;
    const bf16* gA0 = A + (long long)(m0 + sr) * lda + sk;
    const bf16* gA1 = gA0 + (long long)64 * lda;
    const bf16* gB0 = Bt + (long long)(n0 + sr) * ldb + sk;
    const bf16* gB1 = gB0 + (long long)64 * ldb;
    bf16* lA0 = &As[sr][sk];
    bf16* lA1 = &As[sr + 64][sk];
    bf16* lB0 = &Bs[sr][sk];
    bf16* lB1 = &Bs[sr + 64][sk];

    for (int k0 = 0; k0 < K; k0 += 32) {
        __builtin_amdgcn_global_load_lds((gptr_t)(gA0 + k0), (lptr_t)lA0, 16, 0, 0);
        __builtin_amdgcn_global_load_lds((gptr_t)(gA1 + k0), (lptr_t)lA1, 16, 0, 0);
        __builtin_amdgcn_global_load_lds((gptr_t)(gB0 + k0), (lptr_t)lB0, 16, 0, 0);
        __builtin_amdgcn_global_load_lds((gptr_t)(gB1 + k0), (lptr_t)lB1, 16, 0, 0);
        __syncthreads();

        bf16x8 af[4], bfr[4];
#pragma unroll
        for (int mi = 0; mi < 4; mi++)
            af[mi] = *(const bf16x8*)&As[wm * 64 + mi * 16 + lm][lq * 8];
#pragma unroll
        for (int ni = 0; ni < 4; ni++)
            bfr[ni] = *(const bf16x8*)&Bs[wn * 64 + ni * 16 + lm][lq * 8];
#pragma unroll
        for (int mi = 0; mi < 4; mi++)
#pragma unroll
            for (int ni = 0; ni < 4; ni++)
                acc[mi][ni] = __builtin_amdgcn_mfma_f32_16x16x32_bf16(
                    af[mi], bfr[ni], acc[mi][ni], 0, 0, 0);
        __syncthreads();
    }

#pragma unroll
    for (int mi = 0; mi < 4; mi++) {
#pragma unroll
        for (int ni = 0; ni < 4; ni++) {
            int row = m0 + wm * 64 + mi * 16 + lq * 4;
            int col = n0 + wn * 64 + ni * 16 + lm;
#pragma unroll
            for (int r = 0; r < 4; r++) {
                float v = alpha * acc[mi][ni][r];
                long long rr = row + r;
                if constexpr (MODE == 0) {
                    bf16* C = (bf16*)Cv + (long long)z * sCz;
                    C[rr * ldc + col] = (bf16)v;
                } else {
                    float* C = (float*)Cv + (long long)z * sCz;
                    C[rr * ldc + col] = v;
                }
            }
        }
    }
}

// ---------------------------------------------------------------------------
// 256x256 counted-vmcnt pipelined GEMM (T2+T3+T4+T5 stack).
//   C(MxN) = A(MxK) . Bt(NxK)^T, bf16 in, fp32 accum. BK=64, 8 waves (2Mx4N),
//   per-wave 128x64 out, 16x16x32 MFMA, LDS 128 KiB double-buffered.
//   Staging: global_load_lds w=16, LINEAR LDS dest + XOR-swizzled GLOBAL
//   source (kc ^= row&7, 16B chunks); ds_read applies the same XOR.
//   Schedule per K-tile t (buf c=t&1):
//     front-load all 24 frag ds_reads (buf c) -> MFMA ks=0 ->
//     lgkmcnt(0)+barrier (buf c released) -> stage tile t+2 into buf c ->
//     MFMA ks=1 -> vmcnt(8) [t+1 done, t+2 in flight] -> barrier.
//   No pointer arrays (addrspacecast static-init bug): bases via arithmetic.
// MODE 0: C bf16 = alpha*acc            MODE 2: C fp32 atomic += acc
// MODE 3: C bf16 = silu(acc)            MODE 4: C bf16 *= acc
// MODE 5: out[(b*NS+sel[m])*ND+n] atomic += rw[m]*(acc + (z==0)*res)
// ---------------------------------------------------------------------------
__device__ __forceinline__ void stage8(const bf16* __restrict__ gA,
                                       const bf16* __restrict__ gB,
                                       long long stA, long long stB,
                                       char* lA, char* lB, long long koff) {
#pragma unroll
    for (int i = 0; i < 4; i++)
        __builtin_amdgcn_global_load_lds((gptr_t)(gA + i * stA + koff),
                                         (lptr_t)(lA + i * 8192), 16, 0, 0);
#pragma unroll
    for (int i = 0; i < 4; i++)
        __builtin_amdgcn_global_load_lds((gptr_t)(gB + i * stB + koff),
                                         (lptr_t)(lB + i * 8192), 16, 0, 0);
}

template <int MODE>
__global__ __launch_bounds__(512, 2) void gemm256(
    const bf16* __restrict__ A, int lda,
    const bf16* __restrict__ Bt, int ldb,
    void* __restrict__ Cv, int ldc,
    int K, float alpha,
    const float* __restrict__ res, const int* __restrict__ selp,
    const float* __restrict__ rwp, float* __restrict__ outp) {
    __shared__ char smem[131072];   // buf0: A@0 B@32768 | buf1: A@65536 B@98304

    const int tid = threadIdx.x;
    const int lane = tid & 63;
    const int wid = tid >> 6;
    const int wm = wid >> 2, wn = wid & 3;     // 2 x 4 waves
    const int lm = lane & 15, lq = lane >> 4;

    // XCD-bijective block swizzle (all grids have nwg % 8 == 0)
    const int nx = gridDim.x;
    const int nwg = nx * gridDim.y;
    const int orig = blockIdx.y * nx + blockIdx.x;
    const int swz = (orig & 7) * (nwg >> 3) + (orig >> 3);
    const int m0 = (swz / nx) * 256;
    const int n0 = (swz % nx) * 256;
    const long long kz = (long long)blockIdx.z * K;

    // staging: thread stages 16B chunk (row = i*64 + tid>>3, kchunk = tid&7);
    // LDS linear, global source pre-swizzled: kc_src = (tid&7) ^ (row&7)
    const int srow = tid >> 3;
    const int skc = ((tid & 7) ^ (srow & 7)) * 8;
    const bf16* gA = A + (long long)(m0 + srow) * lda + kz + skc;
    const bf16* gB = Bt + (long long)(n0 + srow) * ldb + kz + skc;
    const long long stA = (long long)64 * lda;
    const long long stB = (long long)64 * ldb;

    char* sm = (char*)smem;
    const int sdst = tid * 16;

    // frag read offsets: row*128 + ((ks*4+lq) ^ (lm&7))*16 ; ks=1 is ^64
    // (row&7 == lm&7 since all other row terms are multiples of 8)
    const int aoff = (wm * 128 + lm) * 128 + ((lq ^ (lm & 7)) << 4);
    const int boff = (wn * 64 + lm) * 128 + ((lq ^ (lm & 7)) << 4);

    f32x4 acc[8][4];
#pragma unroll
    for (int i = 0; i < 8; i++)
#pragma unroll
        for (int j = 0; j < 4; j++) {
            f32x4 zz = {0.f, 0.f, 0.f, 0.f};
            acc[i][j] = zz;
        }

    const int NTk = K >> 6;   // >= 16 for all launches here

    stage8(gA, gB, stA, stB, sm + sdst, sm + 32768 + sdst, 0);
    stage8(gA, gB, stA, stB, sm + 65536 + sdst, sm + 98304 + sdst, 64);
    asm volatile("s_waitcnt vmcnt(8)" ::: "memory");   // tile 0 done, tile 1 flying
    __builtin_amdgcn_sched_barrier(0);
    __builtin_amdgcn_s_barrier();
    __builtin_amdgcn_sched_barrier(0);

    for (int t = 0; t < NTk; ++t) {
        char* bA = sm + (t & 1) * 65536;
        char* bB = bA + 32768;

        bf16x8 af0, af1, af2, af3, af4, af5, af6, af7;
        bf16x8 ag0, ag1, ag2, ag3, ag4, ag5, ag6, ag7;
        bf16x8 bf0, bf1, bf2, bf3, bg0, bg1, bg2, bg3;
        af0 = *(const bf16x8*)(bA + (aoff + 0 * 2048));
        af1 = *(const bf16x8*)(bA + (aoff + 1 * 2048));
        af2 = *(const bf16x8*)(bA + (aoff + 2 * 2048));
        af3 = *(const bf16x8*)(bA + (aoff + 3 * 2048));
        af4 = *(const bf16x8*)(bA + (aoff + 4 * 2048));
        af5 = *(const bf16x8*)(bA + (aoff + 5 * 2048));
        af6 = *(const bf16x8*)(bA + (aoff + 6 * 2048));
        af7 = *(const bf16x8*)(bA + (aoff + 7 * 2048));
        bf0 = *(const bf16x8*)(bB + (boff + 0 * 2048));
        bf1 = *(const bf16x8*)(bB + (boff + 1 * 2048));
        bf2 = *(const bf16x8*)(bB + (boff + 2 * 2048));
        bf3 = *(const bf16x8*)(bB + (boff + 3 * 2048));
        ag0 = *(const bf16x8*)(bA + ((aoff ^ 64) + 0 * 2048));
        ag1 = *(const bf16x8*)(bA + ((aoff ^ 64) + 1 * 2048));
        ag2 = *(const bf16x8*)(bA + ((aoff ^ 64) + 2 * 2048));
        ag3 = *(const bf16x8*)(bA + ((aoff ^ 64) + 3 * 2048));
        ag4 = *(const bf16x8*)(bA + ((aoff ^ 64) + 4 * 2048));
        ag5 = *(const bf16x8*)(bA + ((aoff ^ 64) + 5 * 2048));
        ag6 = *(const bf16x8*)(bA + ((aoff ^ 64) + 6 * 2048));
        ag7 = *(const bf16x8*)(bA + ((aoff ^ 64) + 7 * 2048));
        bg0 = *(const bf16x8*)(bB + ((boff ^ 64) + 0 * 2048));
        bg1 = *(const bf16x8*)(bB + ((boff ^ 64) + 1 * 2048));
        bg2 = *(const bf16x8*)(bB + ((boff ^ 64) + 2 * 2048));
        bg3 = *(const bf16x8*)(bB + ((boff ^ 64) + 3 * 2048));

        __builtin_amdgcn_s_setprio(1);
#pragma unroll
        for (int ni = 0; ni < 4; ni++) {
            bf16x8 bb_ = (ni == 0) ? bf0 : (ni == 1) ? bf1 : (ni == 2) ? bf2 : bf3;
            acc[0][ni] = __builtin_amdgcn_mfma_f32_16x16x32_bf16(af0, bb_, acc[0][ni], 0, 0, 0);
            acc[1][ni] = __builtin_amdgcn_mfma_f32_16x16x32_bf16(af1, bb_, acc[1][ni], 0, 0, 0);
            acc[2][ni] = __builtin_amdgcn_mfma_f32_16x16x32_bf16(af2, bb_, acc[2][ni], 0, 0, 0);
            acc[3][ni] = __builtin_amdgcn_mfma_f32_16x16x32_bf16(af3, bb_, acc[3][ni], 0, 0, 0);
            acc[4][ni] = __builtin_amdgcn_mfma_f32_16x16x32_bf16(af4, bb_, acc[4][ni], 0, 0, 0);
            acc[5][ni] = __builtin_amdgcn_mfma_f32_16x16x32_bf16(af5, bb_, acc[5][ni], 0, 0, 0);
            acc[6][ni] = __builtin_amdgcn_mfma_f32_16x16x32_bf16(af6, bb_, acc[6][ni], 0, 0, 0);
            acc[7][ni] = __builtin_amdgcn_mfma_f32_16x16x32_bf16(af7, bb_, acc[7][ni], 0, 0, 0);
        }
        __builtin_amdgcn_s_setprio(0);

        asm volatile("s_waitcnt lgkmcnt(0)" ::: "memory");   // all frag reads landed
        __builtin_amdgcn_sched_barrier(0);
        __builtin_amdgcn_s_barrier();                        // buf c released by all waves
        __builtin_amdgcn_sched_barrier(0);

        if (t + 2 < NTk)
            stage8(gA, gB, stA, stB, bA + sdst, bB + sdst, (long long)(t + 2) * 64);
        __builtin_amdgcn_sched_barrier(0);

        __builtin_amdgcn_s_setprio(1);
#pragma unroll
        for (int ni = 0; ni < 4; ni++) {
            bf16x8 bb_ = (ni == 0) ? bg0 : (ni == 1) ? bg1 : (ni == 2) ? bg2 : bg3;
            acc[0][ni] = __builtin_amdgcn_mfma_f32_16x16x32_bf16(ag0, bb_, acc[0][ni], 0, 0, 0);
            acc[1][ni] = __builtin_amdgcn_mfma_f32_16x16x32_bf16(ag1, bb_, acc[1][ni], 0, 0, 0);
            acc[2][ni] = __builtin_amdgcn_mfma_f32_16x16x32_bf16(ag2, bb_, acc[2][ni], 0, 0, 0);
            acc[3][ni] = __builtin_amdgcn_mfma_f32_16x16x32_bf16(ag3, bb_, acc[3][ni], 0, 0, 0);
            acc[4][ni] = __builtin_amdgcn_mfma_f32_16x16x32_bf16(ag4, bb_, acc[4][ni], 0, 0, 0);
            acc[5][ni] = __builtin_amdgcn_mfma_f32_16x16x32_bf16(ag5, bb_, acc[5][ni], 0, 0, 0);
            acc[6][ni] = __builtin_amdgcn_mfma_f32_16x16x32_bf16(ag6, bb_, acc[6][ni], 0, 0, 0);
            acc[7][ni] = __builtin_amdgcn_mfma_f32_16x16x32_bf16(ag7, bb_, acc[7][ni], 0, 0, 0);
        }
        __builtin_amdgcn_s_setprio(0);

        if (t + 2 < NTk) {
            asm volatile("s_waitcnt vmcnt(8)" ::: "memory");  // t+1 done, t+2 flying
        } else {
            asm volatile("s_waitcnt vmcnt(0)" ::: "memory");  // tail drain
        }
        __builtin_amdgcn_sched_barrier(0);
        __builtin_amdgcn_s_barrier();                         // tile t+1 visible
        __builtin_amdgcn_sched_barrier(0);
    }

#pragma unroll
    for (int mi = 0; mi < 8; mi++) {
#pragma unroll
        for (int ni = 0; ni < 4; ni++) {
            const int row = m0 + wm * 128 + mi * 16 + lq * 4;
            const int col = n0 + wn * 64 + ni * 16 + lm;
#pragma unroll
            for (int r = 0; r < 4; r++) {
                float v = alpha * acc[mi][ni][r];
                long long rr = row + r;
                if constexpr (MODE == 0) {
                    bf16* C = (bf16*)Cv;
                    C[rr * ldc + col] = (bf16)v;
                } else if constexpr (MODE == 2) {
                    float* C = (float*)Cv;
                    unsafeAtomicAdd(&C[rr * ldc + col], v);
                } else if constexpr (MODE == 3) {
                    bf16* C = (bf16*)Cv;
                    C[rr * ldc + col] = (bf16)(v / (1.f + __expf(-v)));
                } else if constexpr (MODE == 4) {
                    bf16* C = (bf16*)Cv;
                    bf16* p = &C[rr * ldc + col];
                    *p = (bf16)((float)*p * v);
                } else {   // MODE 5
                    int bb2 = (int)(rr >> 10);
                    int s = selp[rr];
                    float add = rwp[rr] *
                        (v + (blockIdx.z == 0 ? res[rr * (long long)ND + col] : 0.f));
                    unsafeAtomicAdd(outp + ((long long)bb2 * NS + s) * ND + col, add);
                }
            }
        }
    }
}

// ---------------------------------------------------------------------------
extern "C" void kernel_launch(void* const* d_in, const int* in_sizes, int n_in,
                              void* d_out, int out_size, void* d_ws, size_t ws_size,
                              hipStream_t stream) {
    const float* x  = (const float*)d_in[0];
    const float* fr = (const float*)d_in[2];
    const float* wr = (const float*)d_in[3];
    const float* g1 = (const float*)d_in[4];
    const float* wq = (const float*)d_in[5];
    const float* wk = (const float*)d_in[6];
    const float* wv = (const float*)d_in[7];
    const float* wo = (const float*)d_in[8];
    const float* g2 = (const float*)d_in[9];
    const float* w1 = (const float*)d_in[10];
    const float* w3 = (const float*)d_in[11];
    const float* w2 = (const float*)d_in[12];
    float* out = (float*)d_out;

    char* ws = (char*)d_ws;
    size_t off = 0;
    auto take = [&](size_t bytes) -> char* {
        char* p = ws + off;
        off += (bytes + 255) & ~(size_t)255;
        return p;
    };
    int*   sel    = (int*)take((size_t)NB * NT * 4);
    float* rw     = (float*)take((size_t)NB * NT * 4);
    float* logits = (float*)take((size_t)NB * NS * 4);
    float* xf     = (float*)take((size_t)NB * NT * ND * 4);
    bf16*  hbuf   = (bf16*)take((size_t)NB * NT * ND * 2);
    bf16*  wqkv_t = (bf16*)take((size_t)3 * ND * ND * 2);
    bf16*  wo_t   = (bf16*)take((size_t)ND * ND * 2);
    bf16*  Obuf   = (bf16*)take((size_t)NB * NT * ND * 2);
    char* xr = ws + off;
    // attention-phase overlay
    bf16* QKV = (bf16*)xr;                               // [4096][6144]
    bf16* Qr  = QKV + (size_t)NB * NT * 3 * ND;
    bf16* Kr  = Qr + (size_t)NB * NT * ND;
    bf16* Vt  = Kr + (size_t)NB * NT * ND;
    float* scores = (float*)(Vt + (size_t)NB * NT * ND);
    bf16*  P      = (bf16*)(scores + (size_t)NH * NT * NT);
    // FFN-phase overlay (attention data dead by then)
    bf16* w1_t  = (bf16*)xr;
    bf16* w3_t  = w1_t + (size_t)ND * NF;
    bf16* w2_t  = w3_t + (size_t)ND * NF;
    bf16* inter = w2_t + (size_t)ND * NF;

    router_k<<<NB * NS, 256, 0, stream>>>(x, wr, logits);
    topk_k<<<NB, 1024, 0, stream>>>(logits, sel, rw);
    gather_k<<<(NB * NT * ND / 4) / 256, 256, 0, stream>>>(x, sel, xf);
    rmsnorm_k<<<NB * NT, 256, 0, stream>>>(xf, g1, hbuf);

    dim3 tg(ND / 32, ND / 32);
    transpose_to_bf16<<<tg, 256, 0, stream>>>(wq, wqkv_t, ND, ND);
    transpose_to_bf16<<<tg, 256, 0, stream>>>(wk, wqkv_t + (size_t)ND * ND, ND, ND);
    transpose_to_bf16<<<tg, 256, 0, stream>>>(wv, wqkv_t + (size_t)2 * ND * ND, ND, ND);
    transpose_to_bf16<<<tg, 256, 0, stream>>>(wo, wo_t, ND, ND);

    // fused QKV: [4096 x 2048] x [6144 x 2048]^T -> [4096][6144]
    gemm256<0><<<dim3(3 * ND / 256, NB * NT / 256, 1), 512, 0, stream>>>(
        hbuf, ND, wqkv_t, ND, QKV, 3 * ND, ND, 1.0f,
        nullptr, nullptr, nullptr, nullptr);

    rope_k<<<(NB * NT * NH * 64) / 256, 256, 0, stream>>>(QKV, fr, Qr, Kr, Vt);

    const float scal = 0.08838834764831845f;   // 1/sqrt(128)
    for (int bb = 0; bb < NB; bb++) {
        dim3 gs(NT / 128, NT / 128, NH);
        gemm_bt<1><<<gs, 256, 0, stream>>>(
            Qr + (size_t)bb * NH * NT * NHD, NHD, (long long)NT * NHD,
            Kr + (size_t)bb * NH * NT * NHD, NHD, (long long)NT * NHD,
            scores, (long long)NT * NT, NT, NHD, scal,
            nullptr, nullptr, nullptr, nullptr);
        softmax_k<<<NH * NT, 256, 0, stream>>>(scores, P);
        dim3 gv(NHD / 128, NT / 128, NH);
        gemm_bt<0><<<gv, 256, 0, stream>>>(
            P, NT, (long long)NT * NT,
            Vt + (size_t)bb * NH * NHD * NT, NT, (long long)NHD * NT,
            Obuf + (size_t)bb * NT * ND, NHD, ND, NT, 1.0f,
            nullptr, nullptr, nullptr, nullptr);
    }

    // WO: split-K x2 (K=1024 each), atomic += into xf residual
    gemm256<2><<<dim3(ND / 256, NB * NT / 256, 2), 512, 0, stream>>>(
        Obuf, ND, wo_t, ND, xf, ND, ND / 2, 1.0f,
        nullptr, nullptr, nullptr, nullptr);

    rmsnorm_k<<<NB * NT, 256, 0, stream>>>(xf, g2, hbuf);

    transpose_to_bf16<<<dim3(NF / 32, ND / 32), 256, 0, stream>>>(w1, w1_t, ND, NF);
    transpose_to_bf16<<<dim3(NF / 32, ND / 32), 256, 0, stream>>>(w3, w3_t, ND, NF);
    transpose_to_bf16<<<dim3(ND / 32, NF / 32), 256, 0, stream>>>(w2, w2_t, NF, ND);

    dim3 gf(NF / 256, NB * NT / 256, 1);
    gemm256<3><<<gf, 512, 0, stream>>>(hbuf, ND, w1_t, ND, inter, NF, ND, 1.0f,
                                       nullptr, nullptr, nullptr, nullptr);
    gemm256<4><<<gf, 512, 0, stream>>>(hbuf, ND, w3_t, ND, inter, NF, ND, 1.0f,
                                       nullptr, nullptr, nullptr, nullptr);

    copy_k<<<8192, 256, 0, stream>>>((const float4*)x, (float4*)out,
                                     (long long)NB * NS * ND / 4);
    // w2 + scatter-add: split-K x2 (K=4096 each), res added on z==0 only
    gemm256<5><<<dim3(ND / 256, NB * NT / 256, 2), 512, 0, stream>>>(
        inter, NF, w2_t, NF, nullptr, ND, NF / 2, 1.0f, xf, sel, rw, out);
}